// Round 4
// baseline (550.385 us; speedup 1.0000x reference)
//
#include <hip/hip_runtime.h>
#include <cstdint>
#include <cstddef>

// ---------------------------------------------------------------------------
// Cross_Self_attention: q=xWq+bq, k=xWk+bk, v=yWv+bv, P=softmax(qk^T),
// out = P @ (q*v).  B=8 S=2048 D=H=768, fp32 in/out, fp16 MFMA compute.
//
// Round 4: gemm256 was LDS-BW-bound (192KB frag reads + 64KB stage writes
// per K-tile ~ 3070 cyc vs 620 cyc MFMA; measured 2960 cyc/tile). A-operand
// now bypasses LDS: fragments loaded global->VGPR per wave (L2 serves the
// 4x panel reuse). LDS holds only B (64KB, double-buffered). One barrier
// per K-tile (ph1-end, vmcnt(8) cross-wave gate for B landing + WAR).
// Projections/softmax unchanged.
// ---------------------------------------------------------------------------

#define BM 128
#define BN 128
#define BK 32

using half8 = __attribute__((ext_vector_type(8))) _Float16;  // MFMA A/B frag
using half4 = __attribute__((ext_vector_type(4))) _Float16;
using f32x4 = __attribute__((ext_vector_type(4))) float;     // 4 fp32 acc

// ---------------- fp32 -> fp16 bulk convert (x and y in one dispatch) ------
__global__ __launch_bounds__(256) void cvt2_f32_f16(
    const float* __restrict__ a, const float* __restrict__ b,
    _Float16* __restrict__ oa, _Float16* __restrict__ ob, int n4) {
  const float* in = blockIdx.y ? b : a;
  _Float16* out = blockIdx.y ? ob : oa;
  int i = blockIdx.x * 256 + threadIdx.x;
  if (i >= n4) return;
  float4 v = ((const float4*)in)[i];
  half4 o = {(_Float16)v.x, (_Float16)v.y, (_Float16)v.z, (_Float16)v.w};
  *(half4*)&out[(size_t)i * 4] = o;
}

// ---------------- all three W[768,768] -> W^T fp16 in one dispatch ---------
__global__ __launch_bounds__(256) void tr3_cvt768(
    const float* __restrict__ Wq, const float* __restrict__ Wk,
    const float* __restrict__ Wv, _Float16* __restrict__ Wt) {
  const float* W = (blockIdx.y == 0) ? Wq : (blockIdx.y == 1) ? Wk : Wv;
  _Float16* o = Wt + (size_t)blockIdx.y * 589824;
  int i = blockIdx.x * 256 + threadIdx.x;
  int h = i / 768, d = i - h * 768;
  o[i] = (_Float16)W[d * 768 + h];             // Wt[h][d] = W[d][h]
}

// ---------------- bt-form MFMA GEMM (projections only) ---------------------
// MODE 1: v=acc+bias[n]; g=v*qb[m,n]; gT[(b*768+n)*2048+s]=fp16(g)
// MODE 3: fused q|k proj: n<768 -> Cb=qb (bias), else Cb2=kb (bias2)
template <int MODE>
__global__ __launch_bounds__(256) void gemm_bt(
    const _Float16* __restrict__ Ab, int ldA, long sA,
    const _Float16* __restrict__ Bb, int ldB, long sB,
    void* __restrict__ Cb, int ldc, long sC,
    int K, const float* __restrict__ bias, const _Float16* __restrict__ qb,
    const float* __restrict__ bias2, void* __restrict__ Cb2) {
  __shared__ __align__(16) _Float16 lA[BM * BK];
  __shared__ __align__(16) _Float16 lB[BN * BK];

  const int tid  = threadIdx.x;
  const int lane = tid & 63;
  const int quad = lane >> 4;
  const int l15  = lane & 15;
  const int wave = tid >> 6;
  const int wm = (wave >> 1) * 64;
  const int wn = (wave & 1) * 64;
  const long bm = (long)blockIdx.x * BM;
  const long bn = (long)blockIdx.y * BN;
  const _Float16* A = Ab + (long)blockIdx.z * sA;
  const _Float16* B = Bb + (long)blockIdx.z * sB;

  f32x4 acc[4][4] = {};

  const int c0 = tid,        r0 = c0 >> 2, k0c = (c0 & 3) * 8;
  const int c1 = 256 + tid,  r1 = c1 >> 2, k1c = (c1 & 3) * 8;
  const _Float16* gA0 = A + (size_t)(bm + r0) * ldA + k0c;
  const _Float16* gA1 = A + (size_t)(bm + r1) * ldA + k1c;
  const _Float16* gB0 = B + (size_t)(bn + r0) * ldB + k0c;
  const _Float16* gB1 = B + (size_t)(bn + r1) * ldB + k1c;

  for (int kk = 0; kk < K; kk += BK) {
    __syncthreads();
    __builtin_amdgcn_global_load_lds(
        (const __attribute__((address_space(1))) void*)(gA0 + kk),
        (__attribute__((address_space(3))) void*)&lA[c0 * 8], 16, 0, 0);
    __builtin_amdgcn_global_load_lds(
        (const __attribute__((address_space(1))) void*)(gA1 + kk),
        (__attribute__((address_space(3))) void*)&lA[c1 * 8], 16, 0, 0);
    __builtin_amdgcn_global_load_lds(
        (const __attribute__((address_space(1))) void*)(gB0 + kk),
        (__attribute__((address_space(3))) void*)&lB[c0 * 8], 16, 0, 0);
    __builtin_amdgcn_global_load_lds(
        (const __attribute__((address_space(1))) void*)(gB1 + kk),
        (__attribute__((address_space(3))) void*)&lB[c1 * 8], 16, 0, 0);
    __syncthreads();

    half8 af[4], bfr[4];
#pragma unroll
    for (int i = 0; i < 4; i++) {
      af[i]  = *(const half8*)&lA[(wm + i * 16 + l15) * BK + quad * 8];
      bfr[i] = *(const half8*)&lB[(wn + i * 16 + l15) * BK + quad * 8];
    }
#pragma unroll
    for (int i = 0; i < 4; i++)
#pragma unroll
      for (int j = 0; j < 4; j++)
        acc[i][j] = __builtin_amdgcn_mfma_f32_16x16x32_f16(
            af[i], bfr[j], acc[i][j], 0, 0, 0);
  }

  if constexpr (MODE == 1) {
    __shared__ __align__(16) _Float16 xp[4 * 32 * 72];   // 18 KB
    _Float16* xw = &xp[wave * 2304];
    const long sbase = (bm & 2047) + wm;
    const long bb = bm >> 11;
    const long hbase = bn + wn;
#pragma unroll
    for (int jh = 0; jh < 2; jh++) {
      __syncthreads();
#pragma unroll
      for (int j2 = 0; j2 < 2; j2++) {
        const int j = jh * 2 + j2;
        const long n_g = hbase + j * 16 + l15;
        const float bsv = bias[n_g];
#pragma unroll
        for (int i = 0; i < 4; i++) {
          half4 pk;
#pragma unroll
          for (int r = 0; r < 4; r++) {
            long m_g = bm + wm + i * 16 + quad * 4 + r;
            float v = acc[i][j][r] + bsv;
            float q = (float)qb[m_g * (long)ldc + n_g];
            pk[r] = (_Float16)(v * q);
          }
          *(half4*)&xw[(j2 * 16 + l15) * 72 + i * 16 + quad * 4] = pk;
        }
      }
      __syncthreads();
#pragma unroll
      for (int t = 0; t < 4; t++) {
        const int n_r = t * 8 + (lane >> 3);
        const int m8 = (lane & 7) * 8;
        half8 vv = *(const half8*)&xw[n_r * 72 + m8];
        *(half8*)&((_Float16*)Cb)[(bb * 768 + hbase + 32 * jh + n_r) * 2048 +
                                  sbase + m8] = vv;
      }
    }
  } else {
#pragma unroll
    for (int i = 0; i < 4; i++) {
#pragma unroll
      for (int j = 0; j < 4; j++) {
#pragma unroll
        for (int r = 0; r < 4; r++) {
          long m = bm + wm + i * 16 + quad * 4 + r;
          long n = bn + wn + j * 16 + l15;
          float v = acc[i][j][r];
          if constexpr (MODE == 3) {
            const bool isq = (bn < 768);
            long nn = isq ? n : n - 768;
            v += (isq ? bias : bias2)[nn];
            _Float16* dst = (_Float16*)(isq ? Cb : Cb2);
            dst[m * ldc + nn] = (_Float16)v;
          } else {
            ((float*)Cb + (long)blockIdx.z * sC)[m * ldc + n] = v;
          }
        }
      }
    }
  }
}

// ---------------- 256x256 / BK64 / 8-wave GEMM, A-direct-to-reg ------------
// A: [M][K] fp16 row-major (ldA, per-batch sA). B: bt-form [N][K] (ldB, sB).
// C: fp32 [M][N] (ldc, sC). K multiple of 64, NT=K/64 >= 3.
// LDS 64KB: B only, [buf][half] of 128x64 halfs, XOR-swizzled via
// pre-swizzled global source + swizzled ds_read. A fragments are loaded
// global->VGPR (lane=row l15, quad=k-chunk; 16 rows x 128B contiguous per
// wave -> L2-friendly; L2 serves the panel reuse).
// Per K-tile kt (B buf b = kt&1), 4 quadrant phases:
//  ph0: issue afB(kt) glb->reg; ds_read bfB(kt); MFMA(0,0)[af0,bf0]
//  ph1: MFMA(0,1)[af0,bfB]; s_waitcnt vmcnt(8) lgkmcnt(0); s_barrier
//       (vmcnt(8): last-8-issued = afB(kt) -> B(kt+1) landed in EVERY wave;
//        barrier also orders ph0 B-reads before ph2 STAGE overwrites = WAR)
//  ph2: issue af0(kt+1) glb->reg; STAGE B(kt+2)->buf b; MFMA(1,0)[afB,bf0];
//       ds_read bf0(kt+1) from buf b^1
//  ph3: MFMA(1,1)[afB,bfB]
// A-reg RAW deps are compiler-tracked (it inserts counted vmcnt before use).
__global__ __launch_bounds__(512, 2) void gemm256(
    const _Float16* __restrict__ Ab, int ldA, long sA,
    const _Float16* __restrict__ Bb, int ldB, long sB,
    float* __restrict__ Cb, int ldc, long sC, int K) {
  __shared__ __align__(16) _Float16 ldsB[4][8192];  // [buf*2+half], 64 KB

  const int tid  = threadIdx.x;
  const int lane = tid & 63;
  const int l15  = lane & 15;
  const int quad = lane >> 4;
  const int wave = tid >> 6;
  const int wmi  = wave >> 2;          // 0..1 : M wave index (128 rows each)
  const int wni  = wave & 3;           // 0..3 : N wave index (64 cols each)

  // XCD-chunked swizzle of block index (gridDim.x % 8 == 0)
  const int cpx = gridDim.x >> 3;
  const int l   = blockIdx.x;
  const int nl  = (l & 7) * cpx + (l >> 3);
  const long bm = (long)(nl & 7) * 256;
  const long bn = (long)(nl >> 3) * 256;

  const _Float16* A = Ab + (long)blockIdx.y * sA;
  const _Float16* B = Bb + (long)blockIdx.y * sB;
  float* C = Cb + (long)blockIdx.y * sC;

  // A fragment addressing: uniform base + lane offset.
  const _Float16* aBase = A + (bm + wmi * 128) * (long)ldA;  // wave-uniform
  const int aLane = l15 * ldA + quad * 8;                    // per-lane

  // B staging: source k-offset pre-swizzled so linear LDS holds XOR'd layout.
  const int srow = tid >> 3;
  const int scol = ((tid & 7) ^ (srow & 7)) * 8;
  const _Float16* gB = B + (bn + srow) * (long)ldB + scol;

#define STAGEB(buf, half, kt)                                                  \
  { const _Float16* s0_ = gB + (long)(half) * 128 * ldB + (long)(kt) * 64;     \
    _Float16* d0_ = &ldsB[(buf) * 2 + (half)][tid * 8];                        \
    __builtin_amdgcn_global_load_lds(                                          \
        (const __attribute__((address_space(1))) void*)s0_,                    \
        (__attribute__((address_space(3))) void*)d0_, 16, 0, 0);               \
    __builtin_amdgcn_global_load_lds(                                          \
        (const __attribute__((address_space(1))) void*)(s0_ + 64 * (long)ldB), \
        (__attribute__((address_space(3))) void*)(d0_ + 4096), 16, 0, 0); }

#define LOADA(dst, hrow, kt)                                                   \
  _Pragma("unroll")                                                            \
  for (int i2 = 0; i2 < 4; ++i2)                                               \
    _Pragma("unroll")                                                          \
    for (int ks = 0; ks < 2; ++ks)                                             \
      dst[i2 * 2 + ks] = *(const half8*)(aBase +                               \
          (long)(((hrow) + i2 * 16) * ldA + (kt) * 64 + ks * 32) + aLane);

#define RDB(dst, lbuf, roff)                                                   \
  _Pragma("unroll")                                                            \
  for (int j2 = 0; j2 < 2; ++j2)                                               \
    _Pragma("unroll")                                                          \
    for (int ks = 0; ks < 2; ++ks)                                             \
      dst[j2 * 2 + ks] = *(const half8*)((lbuf) +                              \
          (((roff) + j2 * 16 + l15) * 128 + ((((ks << 2) | quad) << 4) ^ sw4)));

#define MFMAQ(iq, jq, afr, bfr)                                                \
  __builtin_amdgcn_s_setprio(1);                                               \
  _Pragma("unroll")                                                            \
  for (int i2 = 0; i2 < 4; ++i2)                                               \
    _Pragma("unroll")                                                          \
    for (int j2 = 0; j2 < 2; ++j2)                                             \
      _Pragma("unroll")                                                        \
      for (int ks = 0; ks < 2; ++ks)                                           \
        acc[(iq) * 4 + i2][(jq) * 2 + j2] =                                    \
            __builtin_amdgcn_mfma_f32_16x16x32_f16(                            \
                afr[i2 * 2 + ks], bfr[j2 * 2 + ks],                            \
                acc[(iq) * 4 + i2][(jq) * 2 + j2], 0, 0, 0);                   \
  __builtin_amdgcn_s_setprio(0);

  const int NT = K >> 6;
  const int sw4 = (l15 & 7) << 4;      // byte XOR mask for ds_read
  const int rB0 = (wni & 1) * 64;      // row base inside B half-buffer

  f32x4 acc[8][4] = {};
  half8 af0[8], afB[8], bf0[4], bfB[4];

  // prologue: B(0)->buf0, B(1)->buf1 (8 loads), af0(0) (8 loads)
  STAGEB(0, 0, 0) STAGEB(0, 1, 0)
  STAGEB(1, 0, 1) STAGEB(1, 1, 1)
  LOADA(af0, 0, 0)
  asm volatile("s_waitcnt vmcnt(12)" ::: "memory");  // B(0) landed, all waves
  __builtin_amdgcn_s_barrier();
  __builtin_amdgcn_sched_barrier(0);
  {
    const char* lB0 = (const char*)ldsB[(wni >> 1)];
    RDB(bf0, lB0, rB0)
  }

  for (int kt = 0; kt < NT; ++kt) {
    const int b = kt & 1;
    const char* lB  = (const char*)ldsB[b * 2 + (wni >> 1)];
    const char* lBn = (const char*)ldsB[(b ^ 1) * 2 + (wni >> 1)];

    // ---- ph0: issue afB(kt); ds_read bfB(kt); MFMA (0,0) ----
    LOADA(afB, 64, kt)
    RDB(bfB, lB, rB0 + 32)
    MFMAQ(0, 0, af0, bf0)
    __builtin_amdgcn_sched_barrier(0);

    // ---- ph1: MFMA (0,1); cross-wave gate + the tile's one barrier ----
    MFMAQ(0, 1, af0, bfB)
    if (kt + 2 < NT) {
      asm volatile("s_waitcnt vmcnt(8) lgkmcnt(0)" ::: "memory");
    } else {
      asm volatile("s_waitcnt vmcnt(0) lgkmcnt(0)" ::: "memory");
    }
    __builtin_amdgcn_s_barrier();
    __builtin_amdgcn_sched_barrier(0);

    // ---- ph2: issue af0(kt+1) + STAGE B(kt+2); MFMA (1,0); read bf0(kt+1)
    if (kt + 1 < NT) { LOADA(af0, 0, kt + 1) }
    if (kt + 2 < NT) { STAGEB(b, 0, kt + 2) STAGEB(b, 1, kt + 2) }
    MFMAQ(1, 0, afB, bf0)
    if (kt + 1 < NT) { RDB(bf0, lBn, rB0) }
    __builtin_amdgcn_sched_barrier(0);

    // ---- ph3: MFMA (1,1) ----
    MFMAQ(1, 1, afB, bfB)
    __builtin_amdgcn_sched_barrier(0);
  }
#undef STAGEB
#undef LOADA
#undef RDB
#undef MFMAQ

  // epilogue: D layout col=lane&15, row=quad*4+reg
  float* Cp = C + (bm + wmi * 128 + quad * 4) * (long)ldc + bn + wni * 64 + l15;
#pragma unroll
  for (int i = 0; i < 8; ++i)
#pragma unroll
    for (int j = 0; j < 4; ++j)
#pragma unroll
      for (int r = 0; r < 4; ++r)
        Cp[(i * 16 + r) * (long)ldc + j * 16] = acc[i][j][r];
}

// ---------------- row softmax: fp32 scores[row,2048] -> fp16 probs ---------
__global__ __launch_bounds__(256) void softmax_rows(
    const float* __restrict__ sc, _Float16* __restrict__ pr, int prPitch) {
  const int row = blockIdx.x;
  const float* x = sc + (size_t)row * 2048;
  const int t = threadIdx.x;
  float4 v0 = ((const float4*)x)[2 * t];
  float4 v1 = ((const float4*)x)[2 * t + 1];
  float e[8] = {v0.x, v0.y, v0.z, v0.w, v1.x, v1.y, v1.z, v1.w};

  float m = e[0];
#pragma unroll
  for (int i = 1; i < 8; i++) m = fmaxf(m, e[i]);
#pragma unroll
  for (int o = 32; o; o >>= 1) m = fmaxf(m, __shfl_xor(m, o, 64));
  __shared__ float red[4];
  if ((t & 63) == 0) red[t >> 6] = m;
  __syncthreads();
  m = fmaxf(fmaxf(red[0], red[1]), fmaxf(red[2], red[3]));

  float s = 0.f;
#pragma unroll
  for (int i = 0; i < 8; i++) { e[i] = __expf(e[i] - m); s += e[i]; }
#pragma unroll
  for (int o = 32; o; o >>= 1) s += __shfl_xor(s, o, 64);
  __syncthreads();
  if ((t & 63) == 0) red[t >> 6] = s;
  __syncthreads();
  s = red[0] + red[1] + red[2] + red[3];
  float inv = 1.0f / s;

  union { _Float16 h[8]; uint4 v; } o;
#pragma unroll
  for (int i = 0; i < 8; i++) o.h[i] = (_Float16)(e[i] * inv);
  ((uint4*)(pr + (size_t)row * prPitch))[t] = o.v;
}

// ---------------------------------------------------------------------------
extern "C" void kernel_launch(void* const* d_in, const int* in_sizes, int n_in,
                              void* d_out, int out_size, void* d_ws, size_t ws_size,
                              hipStream_t stream) {
  const float* x  = (const float*)d_in[0];
  const float* y  = (const float*)d_in[1];
  const float* Wq = (const float*)d_in[2];
  const float* bq = (const float*)d_in[3];
  const float* Wk = (const float*)d_in[4];
  const float* bk = (const float*)d_in[5];
  const float* Wv = (const float*)d_in[6];
  const float* bv = (const float*)d_in[7];
  float* out = (float*)d_out;

  const int S = 2048, D = 768, H = 768;
  const long SH = (long)S * H;          // 1572864
  char* ws = (char*)d_ws;
  _Float16* qb  = (_Float16*)(ws + 0);
  _Float16* kb  = (_Float16*)(ws + 25165824);
  _Float16* gT  = (_Float16*)(ws + 50331648);
  _Float16* xb  = (_Float16*)(ws + 75497472);
  _Float16* yb  = (_Float16*)(ws + 100663296);
  _Float16* WtQ = (_Float16*)(ws + 125829120);
  _Float16* WtV = WtQ + 2 * 589824;
  float* scores = (float*)(ws + 75497472);

  // 1) prep
  cvt2_f32_f16<<<dim3(12288, 2), 256, 0, stream>>>(x, y, xb, yb, 3145728);
  tr3_cvt768<<<dim3(2304, 3), 256, 0, stream>>>(Wq, Wk, Wv, WtQ);

  // 2) projections (old 128-tile kernel)
  gemm_bt<3><<<dim3(128, 12, 1), 256, 0, stream>>>(
      xb, D, 0, WtQ, D, 0, qb, H, 0, D, bq, nullptr, bk, kb);
  gemm_bt<1><<<dim3(128, 6, 1), 256, 0, stream>>>(
      yb, D, 0, WtV, D, 0, gT, H, 0, D, bv, qb, nullptr, nullptr);

  // 3) attention: A-direct 256-tile GEMMs. probs in-place fp16,
  // pitch 4096 halfs in the first 4KB of each 8KB score row.
  _Float16* probs = (_Float16*)scores;
  if (ws_size >= 209715200ull) {        // Tier A: all 8 batches
    gemm256<<<dim3(64, 8), 512, 0, stream>>>(
        qb, H, SH, kb, H, SH, scores, S, (long)S * S, D);
    softmax_rows<<<16384, 256, 0, stream>>>(scores, probs, 4096);
    gemm256<<<dim3(24, 8), 512, 0, stream>>>(
        probs, 4096, (long)S * 4096, gT, S, SH, out, H, SH, S);
  } else {                              // Tier C: 4 rounds x 2 batches
    for (int r = 0; r < 4; r++) {
      const long b0 = 2 * r;
      gemm256<<<dim3(64, 2), 512, 0, stream>>>(
          qb + b0 * SH, H, SH, kb + b0 * SH, H, SH, scores, S, (long)S * S, D);
      softmax_rows<<<4096, 256, 0, stream>>>(scores, probs, 4096);
      gemm256<<<dim3(24, 2), 512, 0, stream>>>(
          probs, 4096, (long)S * 4096, gT + b0 * SH, S, SH,
          out + b0 * SH, H, SH, S);
    }
  }
}

// Round 5
// 413.838 us; speedup vs baseline: 1.3300x; 1.3300x over previous
//
#include <hip/hip_runtime.h>
#include <cstdint>
#include <cstddef>

// ---------------------------------------------------------------------------
// Cross_Self_attention: q=xWq+bq, k=xWk+bk, v=yWv+bv, P=softmax(qk^T),
// out = P @ (q*v).  B=8 S=2048 D=H=768, fp32 in/out, fp16 MFMA compute.
//
// Round 5: round-4's A-direct experiment REVERTED (latency-serialized: 13%
// MfmaUtil, 1.28 TB/s). gemm256 K-loop restored to the verified round-3
// quadrant schedule. New: epilogue templated (CM=1: bias + fp16 dual-store)
// so the q|k projection (was gemm_bt<3>, 89us @ 435 TF) runs on the same
// 256x256 pipeline (scores GEMM runs this structure ~1.9x faster per FLOP).
// ---------------------------------------------------------------------------

#define BM 128
#define BN 128
#define BK 32

using half8 = __attribute__((ext_vector_type(8))) _Float16;  // MFMA A/B frag
using half4 = __attribute__((ext_vector_type(4))) _Float16;
using f32x4 = __attribute__((ext_vector_type(4))) float;     // 4 fp32 acc

// ---------------- fp32 -> fp16 bulk convert (x and y in one dispatch) ------
__global__ __launch_bounds__(256) void cvt2_f32_f16(
    const float* __restrict__ a, const float* __restrict__ b,
    _Float16* __restrict__ oa, _Float16* __restrict__ ob, int n4) {
  const float* in = blockIdx.y ? b : a;
  _Float16* out = blockIdx.y ? ob : oa;
  int i = blockIdx.x * 256 + threadIdx.x;
  if (i >= n4) return;
  float4 v = ((const float4*)in)[i];
  half4 o = {(_Float16)v.x, (_Float16)v.y, (_Float16)v.z, (_Float16)v.w};
  *(half4*)&out[(size_t)i * 4] = o;
}

// ---------------- all three W[768,768] -> W^T fp16 in one dispatch ---------
__global__ __launch_bounds__(256) void tr3_cvt768(
    const float* __restrict__ Wq, const float* __restrict__ Wk,
    const float* __restrict__ Wv, _Float16* __restrict__ Wt) {
  const float* W = (blockIdx.y == 0) ? Wq : (blockIdx.y == 1) ? Wk : Wv;
  _Float16* o = Wt + (size_t)blockIdx.y * 589824;
  int i = blockIdx.x * 256 + threadIdx.x;
  int h = i / 768, d = i - h * 768;
  o[i] = (_Float16)W[d * 768 + h];             // Wt[h][d] = W[d][h]
}

// ---------------- bt-form MFMA GEMM (v-projection MODE 1 only) -------------
// MODE 1: v=acc+bias[n]; g=v*qb[m,n]; gT[(b*768+n)*2048+s]=fp16(g)
template <int MODE>
__global__ __launch_bounds__(256) void gemm_bt(
    const _Float16* __restrict__ Ab, int ldA, long sA,
    const _Float16* __restrict__ Bb, int ldB, long sB,
    void* __restrict__ Cb, int ldc, long sC,
    int K, const float* __restrict__ bias, const _Float16* __restrict__ qb,
    const float* __restrict__ bias2, void* __restrict__ Cb2) {
  __shared__ __align__(16) _Float16 lA[BM * BK];
  __shared__ __align__(16) _Float16 lB[BN * BK];

  const int tid  = threadIdx.x;
  const int lane = tid & 63;
  const int quad = lane >> 4;
  const int l15  = lane & 15;
  const int wave = tid >> 6;
  const int wm = (wave >> 1) * 64;
  const int wn = (wave & 1) * 64;
  const long bm = (long)blockIdx.x * BM;
  const long bn = (long)blockIdx.y * BN;
  const _Float16* A = Ab + (long)blockIdx.z * sA;
  const _Float16* B = Bb + (long)blockIdx.z * sB;

  f32x4 acc[4][4] = {};

  const int c0 = tid,        r0 = c0 >> 2, k0c = (c0 & 3) * 8;
  const int c1 = 256 + tid,  r1 = c1 >> 2, k1c = (c1 & 3) * 8;
  const _Float16* gA0 = A + (size_t)(bm + r0) * ldA + k0c;
  const _Float16* gA1 = A + (size_t)(bm + r1) * ldA + k1c;
  const _Float16* gB0 = B + (size_t)(bn + r0) * ldB + k0c;
  const _Float16* gB1 = B + (size_t)(bn + r1) * ldB + k1c;

  for (int kk = 0; kk < K; kk += BK) {
    __syncthreads();
    __builtin_amdgcn_global_load_lds(
        (const __attribute__((address_space(1))) void*)(gA0 + kk),
        (__attribute__((address_space(3))) void*)&lA[c0 * 8], 16, 0, 0);
    __builtin_amdgcn_global_load_lds(
        (const __attribute__((address_space(1))) void*)(gA1 + kk),
        (__attribute__((address_space(3))) void*)&lA[c1 * 8], 16, 0, 0);
    __builtin_amdgcn_global_load_lds(
        (const __attribute__((address_space(1))) void*)(gB0 + kk),
        (__attribute__((address_space(3))) void*)&lB[c0 * 8], 16, 0, 0);
    __builtin_amdgcn_global_load_lds(
        (const __attribute__((address_space(1))) void*)(gB1 + kk),
        (__attribute__((address_space(3))) void*)&lB[c1 * 8], 16, 0, 0);
    __syncthreads();

    half8 af[4], bfr[4];
#pragma unroll
    for (int i = 0; i < 4; i++) {
      af[i]  = *(const half8*)&lA[(wm + i * 16 + l15) * BK + quad * 8];
      bfr[i] = *(const half8*)&lB[(wn + i * 16 + l15) * BK + quad * 8];
    }
#pragma unroll
    for (int i = 0; i < 4; i++)
#pragma unroll
      for (int j = 0; j < 4; j++)
        acc[i][j] = __builtin_amdgcn_mfma_f32_16x16x32_f16(
            af[i], bfr[j], acc[i][j], 0, 0, 0);
  }

  if constexpr (MODE == 1) {
    __shared__ __align__(16) _Float16 xp[4 * 32 * 72];   // 18 KB
    _Float16* xw = &xp[wave * 2304];
    const long sbase = (bm & 2047) + wm;
    const long bb = bm >> 11;
    const long hbase = bn + wn;
#pragma unroll
    for (int jh = 0; jh < 2; jh++) {
      __syncthreads();
#pragma unroll
      for (int j2 = 0; j2 < 2; j2++) {
        const int j = jh * 2 + j2;
        const long n_g = hbase + j * 16 + l15;
        const float bsv = bias[n_g];
#pragma unroll
        for (int i = 0; i < 4; i++) {
          half4 pk;
#pragma unroll
          for (int r = 0; r < 4; r++) {
            long m_g = bm + wm + i * 16 + quad * 4 + r;
            float v = acc[i][j][r] + bsv;
            float q = (float)qb[m_g * (long)ldc + n_g];
            pk[r] = (_Float16)(v * q);
          }
          *(half4*)&xw[(j2 * 16 + l15) * 72 + i * 16 + quad * 4] = pk;
        }
      }
      __syncthreads();
#pragma unroll
      for (int t = 0; t < 4; t++) {
        const int n_r = t * 8 + (lane >> 3);
        const int m8 = (lane & 7) * 8;
        half8 vv = *(const half8*)&xw[n_r * 72 + m8];
        *(half8*)&((_Float16*)Cb)[(bb * 768 + hbase + 32 * jh + n_r) * 2048 +
                                  sbase + m8] = vv;
      }
    }
  } else {
#pragma unroll
    for (int i = 0; i < 4; i++) {
#pragma unroll
      for (int j = 0; j < 4; j++) {
#pragma unroll
        for (int r = 0; r < 4; r++) {
          long m = bm + wm + i * 16 + quad * 4 + r;
          long n = bn + wn + j * 16 + l15;
          ((float*)Cb + (long)blockIdx.z * sC)[m * ldc + n] = acc[i][j][r];
        }
      }
    }
  }
}

// ---------------- 256x256 / BK64 / 8-wave quadrant-pipelined GEMM ----------
// Round-3 verified K-loop (unchanged). Epilogue templated:
//  CM=0: fp32 C[m][n] store (scores, PV), per-batch via blockIdx.y.
//  CM=1: fused q|k projection: n<768 -> Cb=q (bias), else Cb2=k (bias2),
//        fp16 store, ldc=768.
// Block decode: nl = XCD-chunked(blockIdx.x); bm=(nl & (2^mbShift-1))*256,
// bn=(nl>>mbShift)*256. gridDim.x % 8 == 0 required.
template <int CM>
__global__ __launch_bounds__(512, 2) void gemm256(
    const _Float16* __restrict__ Ab, int ldA, long sA,
    const _Float16* __restrict__ Bb, int ldB, long sB,
    void* __restrict__ Cb, int ldc, long sC, int K, int mbShift,
    const float* __restrict__ bias, const float* __restrict__ bias2,
    void* __restrict__ Cb2) {
  __shared__ __align__(16) _Float16 lds[8][8192];  // idx = buf*4+op*2+half

  const int tid  = threadIdx.x;
  const int lane = tid & 63;
  const int l15  = lane & 15;
  const int quad = lane >> 4;
  const int wave = tid >> 6;
  const int wmi  = wave >> 2;          // 0..1 : M wave index (128 rows each)
  const int wni  = wave & 3;           // 0..3 : N wave index (64 cols each)

  // XCD-chunked swizzle of block index (gridDim.x % 8 == 0)
  const int cpx = gridDim.x >> 3;
  const int l   = blockIdx.x;
  const int nl  = (l & 7) * cpx + (l >> 3);
  const long bm = (long)(nl & ((1 << mbShift) - 1)) * 256;
  const long bn = (long)(nl >> mbShift) * 256;

  const _Float16* A = Ab + (long)blockIdx.y * sA;
  const _Float16* B = Bb + (long)blockIdx.y * sB;

  // staging addresses: source k-offset pre-swizzled so linear LDS holds the
  // XOR'd layout (swizzle must be both-sides-or-neither with gload_lds).
  const int srow = tid >> 3;
  const int scol = ((tid & 7) ^ (srow & 7)) * 8;
  const _Float16* gA = A + (bm + srow) * (long)ldA + scol;
  const _Float16* gB = B + (bn + srow) * (long)ldB + scol;

#define STAGE(op, GP, LD, buf, half, kt)                                       \
  { const _Float16* s0_ = (GP) + (long)(half) * 128 * (LD) + (long)(kt) * 64;  \
    _Float16* d0_ = &lds[(buf) * 4 + (op) * 2 + (half)][tid * 8];              \
    __builtin_amdgcn_global_load_lds(                                          \
        (const __attribute__((address_space(1))) void*)s0_,                    \
        (__attribute__((address_space(3))) void*)d0_, 16, 0, 0);               \
    __builtin_amdgcn_global_load_lds(                                          \
        (const __attribute__((address_space(1))) void*)(s0_ + 64 * (long)(LD)),\
        (__attribute__((address_space(3))) void*)(d0_ + 4096), 16, 0, 0); }

  const int NT = K >> 6;
  const int sw4 = (l15 & 7) << 4;      // byte XOR mask for ds_read
  const int rB0 = (wni & 1) * 64;      // row base inside B half-buffer

  f32x4 acc[8][4] = {};
  half8 af0[8], afB[8], bf0[4], bfB[4];   // h0 / h1 fragment sets

  // prologue: tile0 (A,B) then tile1 (A,B) -> 16 loads; vmcnt(8) = T0 landed
  STAGE(0, gA, ldA, 0, 0, 0) STAGE(0, gA, ldA, 0, 1, 0)
  STAGE(1, gB, ldB, 0, 0, 0) STAGE(1, gB, ldB, 0, 1, 0)
  STAGE(0, gA, ldA, 1, 0, 1) STAGE(0, gA, ldA, 1, 1, 1)
  STAGE(1, gB, ldB, 1, 0, 1) STAGE(1, gB, ldB, 1, 1, 1)
  asm volatile("s_waitcnt vmcnt(8)" ::: "memory");
  __builtin_amdgcn_s_barrier();
  __builtin_amdgcn_sched_barrier(0);

  {  // head reads: af0/bf0 of tile 0 (buf 0)
    const char* lA = (const char*)lds[wmi];
    const char* lB = (const char*)lds[2 + (wni >> 1)];
#pragma unroll
    for (int i2 = 0; i2 < 4; ++i2)
#pragma unroll
      for (int ks = 0; ks < 2; ++ks)
        af0[i2 * 2 + ks] = *(const half8*)(lA + ((i2 * 16 + l15) * 128 +
                                           ((((ks << 2) | quad) << 4) ^ sw4)));
#pragma unroll
    for (int j2 = 0; j2 < 2; ++j2)
#pragma unroll
      for (int ks = 0; ks < 2; ++ks)
        bf0[j2 * 2 + ks] = *(const half8*)(lB + ((rB0 + j2 * 16 + l15) * 128 +
                                           ((((ks << 2) | quad) << 4) ^ sw4)));
    asm volatile("s_waitcnt lgkmcnt(0)" ::: "memory");
    __builtin_amdgcn_s_barrier();
    __builtin_amdgcn_sched_barrier(0);
  }

  for (int kt = 0; kt < NT; ++kt) {
    const int b = kt & 1;
    const char* lA  = (const char*)lds[b * 4 + wmi];
    const char* lB  = (const char*)lds[b * 4 + 2 + (wni >> 1)];
    const char* lAn = (const char*)lds[(b ^ 1) * 4 + wmi];
    const char* lBn = (const char*)lds[(b ^ 1) * 4 + 2 + (wni >> 1)];

    // ---------------- ph0: read bfB(h1); MFMA quadrant (0,0) --------------
#pragma unroll
    for (int j2 = 0; j2 < 2; ++j2)
#pragma unroll
      for (int ks = 0; ks < 2; ++ks)
        bfB[j2 * 2 + ks] = *(const half8*)(lB + ((rB0 + 32 + j2 * 16 + l15) * 128 +
                                           ((((ks << 2) | quad) << 4) ^ sw4)));
    __builtin_amdgcn_s_setprio(1);
#pragma unroll
    for (int i2 = 0; i2 < 4; ++i2)
#pragma unroll
      for (int j2 = 0; j2 < 2; ++j2)
#pragma unroll
        for (int ks = 0; ks < 2; ++ks)
          acc[i2][j2] = __builtin_amdgcn_mfma_f32_16x16x32_f16(
              af0[i2 * 2 + ks], bf0[j2 * 2 + ks], acc[i2][j2], 0, 0, 0);
    __builtin_amdgcn_s_setprio(0);
    asm volatile("s_waitcnt lgkmcnt(0)" ::: "memory");
    __builtin_amdgcn_s_barrier();
    __builtin_amdgcn_sched_barrier(0);

    // ---------------- ph1: read afB(h1); stage B(kt+2); MFMA (0,1); gate --
#pragma unroll
    for (int i2 = 0; i2 < 4; ++i2)
#pragma unroll
      for (int ks = 0; ks < 2; ++ks)
        afB[i2 * 2 + ks] = *(const half8*)(lA + ((64 + i2 * 16 + l15) * 128 +
                                           ((((ks << 2) | quad) << 4) ^ sw4)));
    if (kt + 2 < NT) {
      STAGE(1, gB, ldB, b, 0, kt + 2)
      STAGE(1, gB, ldB, b, 1, kt + 2)
    }
    __builtin_amdgcn_s_setprio(1);
#pragma unroll
    for (int i2 = 0; i2 < 4; ++i2)
#pragma unroll
      for (int j2 = 0; j2 < 2; ++j2)
#pragma unroll
        for (int ks = 0; ks < 2; ++ks)
          acc[i2][2 + j2] = __builtin_amdgcn_mfma_f32_16x16x32_f16(
              af0[i2 * 2 + ks], bfB[j2 * 2 + ks], acc[i2][2 + j2], 0, 0, 0);
    __builtin_amdgcn_s_setprio(0);
    asm volatile("s_waitcnt lgkmcnt(0)" ::: "memory");
    if (kt + 2 < NT) {
      asm volatile("s_waitcnt vmcnt(4)" ::: "memory");   // tile kt+1 landed
    } else if (kt + 1 < NT) {
      asm volatile("s_waitcnt vmcnt(0)" ::: "memory");   // final drain
    }
    __builtin_amdgcn_s_barrier();
    __builtin_amdgcn_sched_barrier(0);

    // ---------------- ph2: stage A(kt+2); MFMA (1,0); read bf0(kt+1,h0) ---
    if (kt + 2 < NT) {
      STAGE(0, gA, ldA, b, 0, kt + 2)
      STAGE(0, gA, ldA, b, 1, kt + 2)
    }
    __builtin_amdgcn_s_setprio(1);
#pragma unroll
    for (int i2 = 0; i2 < 4; ++i2)
#pragma unroll
      for (int j2 = 0; j2 < 2; ++j2)
#pragma unroll
        for (int ks = 0; ks < 2; ++ks)
          acc[4 + i2][j2] = __builtin_amdgcn_mfma_f32_16x16x32_f16(
              afB[i2 * 2 + ks], bf0[j2 * 2 + ks], acc[4 + i2][j2], 0, 0, 0);
    __builtin_amdgcn_s_setprio(0);
    if (kt + 1 < NT) {
#pragma unroll
      for (int j2 = 0; j2 < 2; ++j2)
#pragma unroll
        for (int ks = 0; ks < 2; ++ks)
          bf0[j2 * 2 + ks] = *(const half8*)(lBn + ((rB0 + j2 * 16 + l15) * 128 +
                                             ((((ks << 2) | quad) << 4) ^ sw4)));
    }
    asm volatile("s_waitcnt lgkmcnt(0)" ::: "memory");
    __builtin_amdgcn_s_barrier();
    __builtin_amdgcn_sched_barrier(0);

    // ---------------- ph3: MFMA (1,1); read af0(kt+1,h0) ------------------
    __builtin_amdgcn_s_setprio(1);
#pragma unroll
    for (int i2 = 0; i2 < 4; ++i2)
#pragma unroll
      for (int j2 = 0; j2 < 2; ++j2)
#pragma unroll
        for (int ks = 0; ks < 2; ++ks)
          acc[4 + i2][2 + j2] = __builtin_amdgcn_mfma_f32_16x16x32_f16(
              afB[i2 * 2 + ks], bfB[j2 * 2 + ks], acc[4 + i2][2 + j2], 0, 0, 0);
    __builtin_amdgcn_s_setprio(0);
    if (kt + 1 < NT) {
#pragma unroll
      for (int i2 = 0; i2 < 4; ++i2)
#pragma unroll
        for (int ks = 0; ks < 2; ++ks)
          af0[i2 * 2 + ks] = *(const half8*)(lAn + ((i2 * 16 + l15) * 128 +
                                             ((((ks << 2) | quad) << 4) ^ sw4)));
    }
    asm volatile("s_waitcnt lgkmcnt(0)" ::: "memory");
    __builtin_amdgcn_s_barrier();
    __builtin_amdgcn_sched_barrier(0);
  }
#undef STAGE

  // epilogue: D layout col=lane&15, row=quad*4+reg
  if constexpr (CM == 0) {
    float* Cp = (float*)Cb + (long)blockIdx.y * sC +
                (bm + wmi * 128 + quad * 4) * (long)ldc + bn + wni * 64 + l15;
#pragma unroll
    for (int i = 0; i < 8; ++i)
#pragma unroll
      for (int j = 0; j < 4; ++j)
#pragma unroll
        for (int r = 0; r < 4; ++r)
          Cp[(i * 16 + r) * (long)ldc + j * 16] = acc[i][j][r];
  } else {
    // fused q|k: block-uniform split at n=768, +bias, fp16 store
    const bool isq = (bn < 768);
    _Float16* dst = (_Float16*)(isq ? Cb : Cb2);
    const float* bs = isq ? bias : bias2;
    const long nb = bn - (isq ? 0 : 768) + wni * 64;
    const long mb0 = bm + wmi * 128 + quad * 4;
#pragma unroll
    for (int j = 0; j < 4; ++j) {
      const long nn = nb + j * 16 + l15;
      const float bsv = bs[nn];
#pragma unroll
      for (int i = 0; i < 8; ++i)
#pragma unroll
        for (int r = 0; r < 4; ++r)
          dst[(mb0 + i * 16 + r) * (long)ldc + nn] =
              (_Float16)(acc[i][j][r] + bsv);
    }
  }
}

// ---------------- row softmax: fp32 scores[row,2048] -> fp16 probs ---------
__global__ __launch_bounds__(256) void softmax_rows(
    const float* __restrict__ sc, _Float16* __restrict__ pr, int prPitch) {
  const int row = blockIdx.x;
  const float* x = sc + (size_t)row * 2048;
  const int t = threadIdx.x;
  float4 v0 = ((const float4*)x)[2 * t];
  float4 v1 = ((const float4*)x)[2 * t + 1];
  float e[8] = {v0.x, v0.y, v0.z, v0.w, v1.x, v1.y, v1.z, v1.w};

  float m = e[0];
#pragma unroll
  for (int i = 1; i < 8; i++) m = fmaxf(m, e[i]);
#pragma unroll
  for (int o = 32; o; o >>= 1) m = fmaxf(m, __shfl_xor(m, o, 64));
  __shared__ float red[4];
  if ((t & 63) == 0) red[t >> 6] = m;
  __syncthreads();
  m = fmaxf(fmaxf(red[0], red[1]), fmaxf(red[2], red[3]));

  float s = 0.f;
#pragma unroll
  for (int i = 0; i < 8; i++) { e[i] = __expf(e[i] - m); s += e[i]; }
#pragma unroll
  for (int o = 32; o; o >>= 1) s += __shfl_xor(s, o, 64);
  __syncthreads();
  if ((t & 63) == 0) red[t >> 6] = s;
  __syncthreads();
  s = red[0] + red[1] + red[2] + red[3];
  float inv = 1.0f / s;

  union { _Float16 h[8]; uint4 v; } o;
#pragma unroll
  for (int i = 0; i < 8; i++) o.h[i] = (_Float16)(e[i] * inv);
  ((uint4*)(pr + (size_t)row * prPitch))[t] = o.v;
}

// ---------------------------------------------------------------------------
extern "C" void kernel_launch(void* const* d_in, const int* in_sizes, int n_in,
                              void* d_out, int out_size, void* d_ws, size_t ws_size,
                              hipStream_t stream) {
  const float* x  = (const float*)d_in[0];
  const float* y  = (const float*)d_in[1];
  const float* Wq = (const float*)d_in[2];
  const float* bq = (const float*)d_in[3];
  const float* Wk = (const float*)d_in[4];
  const float* bk = (const float*)d_in[5];
  const float* Wv = (const float*)d_in[6];
  const float* bv = (const float*)d_in[7];
  float* out = (float*)d_out;

  const int S = 2048, D = 768, H = 768;
  const long SH = (long)S * H;          // 1572864
  char* ws = (char*)d_ws;
  _Float16* qb  = (_Float16*)(ws + 0);
  _Float16* kb  = (_Float16*)(ws + 25165824);
  _Float16* gT  = (_Float16*)(ws + 50331648);
  _Float16* xb  = (_Float16*)(ws + 75497472);
  _Float16* yb  = (_Float16*)(ws + 100663296);
  _Float16* WtQ = (_Float16*)(ws + 125829120);
  _Float16* WtV = WtQ + 2 * 589824;
  float* scores = (float*)(ws + 75497472);

  // 1) prep
  cvt2_f32_f16<<<dim3(12288, 2), 256, 0, stream>>>(x, y, xb, yb, 3145728);
  tr3_cvt768<<<dim3(2304, 3), 256, 0, stream>>>(Wq, Wk, Wv, WtQ);

  // 2) projections: fused q|k on the 256-tile pipeline (M=16384, N=1536,
  //    K=768; 64 M-blocks x 6 N-blocks = 384, %8==0). v-proj unchanged.
  gemm256<1><<<dim3(384, 1), 512, 0, stream>>>(
      xb, D, 0, WtQ, D, 0, qb, H, 0, D, 6, bq, bk, kb);
  gemm_bt<1><<<dim3(128, 6, 1), 256, 0, stream>>>(
      yb, D, 0, WtV, D, 0, gT, H, 0, D, bv, qb, nullptr, nullptr);

  // 3) attention: quadrant-pipelined 256-tile GEMMs. probs in-place fp16,
  // pitch 4096 halfs in the first 4KB of each 8KB score row.
  _Float16* probs = (_Float16*)scores;
  if (ws_size >= 209715200ull) {        // Tier A: all 8 batches
    gemm256<0><<<dim3(64, 8), 512, 0, stream>>>(
        qb, H, SH, kb, H, SH, scores, S, (long)S * S, D, 3,
        nullptr, nullptr, nullptr);
    softmax_rows<<<16384, 256, 0, stream>>>(scores, probs, 4096);
    gemm256<0><<<dim3(24, 8), 512, 0, stream>>>(
        probs, 4096, (long)S * 4096, gT, S, SH, out, H, SH, S, 3,
        nullptr, nullptr, nullptr);
  } else {                              // Tier C: 4 rounds x 2 batches
    for (int r = 0; r < 4; r++) {
      const long b0 = 2 * r;
      gemm256<0><<<dim3(64, 2), 512, 0, stream>>>(
          qb + b0 * SH, H, SH, kb + b0 * SH, H, SH, scores, S, (long)S * S,
          D, 3, nullptr, nullptr, nullptr);
      softmax_rows<<<4096, 256, 0, stream>>>(scores, probs, 4096);
      gemm256<0><<<dim3(24, 2), 512, 0, stream>>>(
          probs, 4096, (long)S * 4096, gT + b0 * SH, S, SH,
          out + b0 * SH, H, SH, S, 3, nullptr, nullptr, nullptr);
    }
  }
}